// Round 5
// baseline (84.662 us; speedup 1.0000x reference)
//
#include <hip/hip_runtime.h>

#define STEPS 32
#define H 256
#define W 256
#define R 8                // rows per wave band
#define NIMG 192
#define BLOCKS_PER_IMG 8   // 4 waves/block * 8 rows/wave = 32 rows/block

// bin(f) = ceil(f*31). Input uniform [0,1): k in [0,31], no clip needed
// (absmax exactly 0 in R1-R4). Monotone => bin(max(a,b)) = max(bin a, bin b).
__device__ __forceinline__ int binf(float f) {
    return (int)ceilf(f * 31.0f);
}

// Chain-form ECC histogram. Per column chain a_0..a_255 (vertex bins):
//   sum_i(+a_i) - sum_i(max(a_i,a_{i+1})) telescopes to: per transition i,
//   contribute (+1@a_i, -1@a_{i+1}) ONLY when a_{i+1} > a_i; plus +1@a_255.
// H-edges+squares are the same chain on he_i = max(v_i, v_i_right), negated:
//   when rising: (-1@he_i, +1@he_{i+1}); end term -1@he_255.
// This halves LDS-atomic active lanes (~47% rising) and deletes the
// v-edge/square max() work. The DS pipe (atomic RMW) is the R4 bottleneck.
// hist[k*64 + lane]: bank = lane%32 (2-way aliasing per wave64 = free).
__global__ __launch_bounds__(256) void ecc_kernel(const float* __restrict__ x,
                                                  float* __restrict__ out) {
    __shared__ int hist[STEPS * 64];   // 8 KB
    const int tid  = threadIdx.x;
    const int lane = tid & 63;
    const int wave = tid >> 6;
    const int bc   = blockIdx.x >> 3;  // image*channel 0..191
    const int bg   = blockIdx.x & 7;   // band group within image
    const int r0   = (bg * 4 + wave) * R;
    // lane owns cols 4*lane..4*lane+3
    const float4* rowp = (const float4*)(x + (size_t)bc * (H * W)) + lane;

#pragma unroll
    for (int w = 0; w < 8; ++w) hist[(w << 8) + tid] = 0;
    __syncthreads();

    const bool has_right = (lane < 63);     // col 255 has no right edge
    const bool last_band = (r0 + R == H);

#define ADD(k, v) atomicAdd(&hist[((k) << 6) + lane], (v))

    // 5-slot register queue, rows r0..r0+4
    float4 q[5];
#pragma unroll
    for (int t = 0; t < 5; ++t) q[t] = rowp[(size_t)(r0 + t) * (W / 4)];

    int c0 = binf(q[0].x), c1 = binf(q[0].y), c2 = binf(q[0].z), c3 = binf(q[0].w);
    int cR = __shfl_down(c0, 1);
    int h0 = max(c0, c1), h1 = max(c1, c2), h2 = max(c2, c3), h3 = max(c3, cR);

#pragma unroll
    for (int t = 0; t < R; ++t) {
        const bool down = (t < R - 1) || !last_band;   // wave-uniform
        if (down) {
            float4 nq = q[(t + 1) % 5];
            int n0 = binf(nq.x), n1 = binf(nq.y), n2 = binf(nq.z), n3 = binf(nq.w);
            int nR = __shfl_down(n0, 1);
            int g0 = max(n0, n1), g1 = max(n1, n2), g2 = max(n2, n3), g3 = max(n3, nR);
            // prefetch row r0+t+5 into the freed slot
            if (t <= 3 && (t < 3 || !last_band))
                q[t % 5] = rowp[(size_t)(r0 + t + 5) * (W / 4)];
            // vertex/v-edge chain: contribute only on strict rise
            if (n0 > c0) { ADD(c0, 1); ADD(n0, -1); }
            if (n1 > c1) { ADD(c1, 1); ADD(n1, -1); }
            if (n2 > c2) { ADD(c2, 1); ADD(n2, -1); }
            if (n3 > c3) { ADD(c3, 1); ADD(n3, -1); }
            // h-edge/square chain (negated): contribute only on strict rise
            if (g0 > h0) { ADD(h0, -1); ADD(g0, 1); }
            if (g1 > h1) { ADD(h1, -1); ADD(g1, 1); }
            if (g2 > h2) { ADD(h2, -1); ADD(g2, 1); }
            if (has_right && g3 > h3) { ADD(h3, -1); ADD(g3, 1); }
            c0 = n0; c1 = n1; c2 = n2; c3 = n3;
            h0 = g0; h1 = g1; h2 = g2; h3 = g3;
        } else {
            // i == 255 (last band only): chain end terms = row-255 vertices (+)
            // and row-255 h-edges (-)
            ADD(c0, 1); ADD(c1, 1); ADD(c2, 1); ADD(c3, 1);
            ADD(h0, -1); ADD(h1, -1); ADD(h2, -1);
            if (has_right) ADD(h3, -1);
        }
    }
#undef ADD
    __syncthreads();

    // 32 threads: sum own bin over 64 columns (rotated => distinct banks),
    // 5-step shfl_up inclusive scan = cumsum, global atomic merges bands.
    if (tid < STEPS) {
        int s = 0;
#pragma unroll 8
        for (int t = 0; t < 64; ++t)
            s += hist[(tid << 6) + ((t + tid) & 63)];
#pragma unroll
        for (int d = 1; d < STEPS; d <<= 1) {
            int u = __shfl_up(s, d);
            if (tid >= d) s += u;
        }
        atomicAdd(&out[bc * STEPS + tid], (float)s);
    }
}

extern "C" void kernel_launch(void* const* d_in, const int* in_sizes, int n_in,
                              void* d_out, int out_size, void* d_ws, size_t ws_size,
                              hipStream_t stream) {
    const float* x = (const float*)d_in[0];
    float* out = (float*)d_out;
    // d_out is re-poisoned before every launch; we accumulate atomically into it.
    hipMemsetAsync(out, 0, (size_t)out_size * sizeof(float), stream);
    ecc_kernel<<<NIMG * BLOCKS_PER_IMG, 256, 0, stream>>>(x, out);
}